// Round 13
// baseline (23486.653 us; speedup 1.0000x reference)
//
#include <hip/hip_runtime.h>
#include <hip/hip_bf16.h>
#include <stdint.h>

#define BS 512
#define D 1024
#define H 4096
#define T_STEPS 64
#define N_INNER 4
#define SK 4

typedef __attribute__((ext_vector_type(8))) _Float16 f16x8;
typedef __attribute__((ext_vector_type(4))) float f32x4;
typedef __attribute__((ext_vector_type(4))) unsigned short u16x4;
typedef unsigned short u16;

__device__ __forceinline__ u16 f2h_bits(float f) {
    _Float16 h = (_Float16)f;
    return __builtin_bit_cast(u16, h);
}
__device__ __forceinline__ float h2f(u16 b) {
    return (float)__builtin_bit_cast(_Float16, b);
}
__device__ __forceinline__ float fast_tanh(float x) {
    float e = __expf(2.0f * x);
    return 1.0f - 2.0f / (e + 1.0f);
}

// ---------------- prep kernels ----------------

// src [rows][cols] f32 -> dst_hi/dst_lo [cols][rows] fp16 (hi + residual lo)
__global__ __launch_bounds__(256) void transpose_split(
    const float* __restrict__ src, u16* __restrict__ dst_hi,
    u16* __restrict__ dst_lo, int rows, int cols) {
    __shared__ float tile[32][33];
    const int tx = threadIdx.x & 31;
    const int ty = threadIdx.x >> 5;
    const int c0 = blockIdx.x * 32, r0 = blockIdx.y * 32;
    #pragma unroll
    for (int i = ty; i < 32; i += 8)
        tile[i][tx] = src[(size_t)(r0 + i) * cols + c0 + tx];
    __syncthreads();
    #pragma unroll
    for (int i = ty; i < 32; i += 8) {
        const float v = tile[tx][i];
        const u16 hi = f2h_bits(v);
        const u16 lo = f2h_bits(v - h2f(hi));
        const size_t idx = (size_t)(c0 + i) * rows + r0 + tx;
        dst_hi[idx] = hi;
        dst_lo[idx] = lo;
    }
}

__global__ __launch_bounds__(256) void init_z(
    const float* __restrict__ z0, float* __restrict__ z_cur,
    u16* __restrict__ z_h, float* __restrict__ out) {
    const int i = blockIdx.x * 256 + threadIdx.x;
    const float v = z0[i];
    z_cur[i] = v;
    z_h[i] = f2h_bits(v);
    out[i] = v;
}

// ---------------- fused fp16 GEMM: ZERO-LDS direct streaming ----------------
// C = A[M][K] @ BT[N][K]^T ; A single fp16, B split hi/lo (2 MFMA terms).
// Both operands loaded straight from cache to registers (16B/lane gathers,
// same pattern r12 proved numerically exact for A). No LDS, no barriers,
// no vmcnt choreography -> compiler software-pipelines the load+MFMA
// stream; 4 blocks/CU (16 waves) hide cache latency.
// 64x64 tile, 4 waves (2x2) of 32x32; K consumed in 32-wide chunks.
// EPI==0: GEMM1 (K=1024, N=4096): hid = tanh(C+b1) fp16.
// EPI==1: GEMM2 split-K (4 x K=1024, N=1024): fp32 partials.
// XCD-grouped maps keep per-XCD weight slice = 2 MB (L2-resident).
template<int EPI>
__global__ __launch_bounds__(256, 4) void gemm_step(
    const u16* __restrict__ A_h,
    const u16* __restrict__ B_hi, const u16* __restrict__ B_lo,
    const float* __restrict__ bias,
    u16* __restrict__ hid_out,
    float* __restrict__ part) {
    const int tid = threadIdx.x;
    const int bid = blockIdx.x;
    const int xcd = bid & 7, loc = bid >> 3;
    int tm, tn, sk, ldK;
    if (EPI == 0) {       // 8 tm x 64 tn; XCD owns 8 consecutive tn
        tn = xcd * 8 + (loc & 7);
        tm = loc >> 3;
        sk = 0;  ldK = D;
    } else {              // 4 sk x 8 tm x 16 tn; XCD owns 2 consecutive tn
        tn = xcd * 2 + (loc & 1);
        tm = (loc >> 1) & 7;
        sk = loc >> 4;  ldK = H;
    }
    const int m0 = tm * 64, n0 = tn * 64;
    const int k0b = sk * 1024;

    const int wave = tid >> 6;
    const int lane = tid & 63;
    const int wr = wave >> 1, wc = wave & 1;
    const int l15 = lane & 15;
    const int lgrp = lane >> 4;
    const int lk8 = lgrp * 8;

    // per-lane row base pointers (A: 2 mi rows; B: 2 ni rows, hi+lo)
    const u16* arow0 = A_h + (size_t)(m0 + wr * 32 + l15) * ldK + k0b + lk8;
    const u16* arow1 = arow0 + (size_t)16 * ldK;
    const u16* brh0 = B_hi + (size_t)(n0 + wc * 32 + l15) * ldK + k0b + lk8;
    const u16* brh1 = brh0 + (size_t)16 * ldK;
    const u16* brl0 = B_lo + (size_t)(n0 + wc * 32 + l15) * ldK + k0b + lk8;
    const u16* brl1 = brl0 + (size_t)16 * ldK;

    f32x4 acc[2][2];
    #pragma unroll
    for (int mi = 0; mi < 2; ++mi)
        #pragma unroll
        for (int ni = 0; ni < 2; ++ni)
            acc[mi][ni] = (f32x4){0.f, 0.f, 0.f, 0.f};

    // K loop: 32 chunks of K=32; 6 gathers + 8 MFMA per chunk.
    // unroll 4 -> compiler interleaves ~24 loads ahead of MFMA stream.
    #pragma unroll 4
    for (int k = 0; k < 1024; k += 32) {
        const f16x8 a0  = *(const f16x8*)(arow0 + k);
        const f16x8 a1  = *(const f16x8*)(arow1 + k);
        const f16x8 bh0 = *(const f16x8*)(brh0 + k);
        const f16x8 bh1 = *(const f16x8*)(brh1 + k);
        const f16x8 bl0 = *(const f16x8*)(brl0 + k);
        const f16x8 bl1 = *(const f16x8*)(brl1 + k);
        acc[0][0] = __builtin_amdgcn_mfma_f32_16x16x32_f16(a0, bh0, acc[0][0], 0, 0, 0);
        acc[0][1] = __builtin_amdgcn_mfma_f32_16x16x32_f16(a0, bh1, acc[0][1], 0, 0, 0);
        acc[1][0] = __builtin_amdgcn_mfma_f32_16x16x32_f16(a1, bh0, acc[1][0], 0, 0, 0);
        acc[1][1] = __builtin_amdgcn_mfma_f32_16x16x32_f16(a1, bh1, acc[1][1], 0, 0, 0);
        acc[0][0] = __builtin_amdgcn_mfma_f32_16x16x32_f16(a0, bl0, acc[0][0], 0, 0, 0);
        acc[0][1] = __builtin_amdgcn_mfma_f32_16x16x32_f16(a0, bl1, acc[0][1], 0, 0, 0);
        acc[1][0] = __builtin_amdgcn_mfma_f32_16x16x32_f16(a1, bl0, acc[1][0], 0, 0, 0);
        acc[1][1] = __builtin_amdgcn_mfma_f32_16x16x32_f16(a1, bl1, acc[1][1], 0, 0, 0);
    }

    // ---- epilogue (r12-identical) ----
    const int crow_base = m0 + wr * 32;
    const int ccol_base = n0 + wc * 32;
    if (EPI == 0) {
        #pragma unroll
        for (int mi = 0; mi < 2; ++mi)
            #pragma unroll
            for (int ni = 0; ni < 2; ++ni) {
                const int col = ccol_base + ni * 16 + l15;
                const float b = bias[col];
                #pragma unroll
                for (int r = 0; r < 4; ++r) {
                    const int row = crow_base + mi * 16 + lgrp * 4 + r;
                    const float v = fast_tanh(acc[mi][ni][r] + b);
                    hid_out[(size_t)row * H + col] = f2h_bits(v);
                }
            }
    } else {
        float* p = part + (size_t)sk * BS * D;
        #pragma unroll
        for (int mi = 0; mi < 2; ++mi)
            #pragma unroll
            for (int ni = 0; ni < 2; ++ni) {
                const int col = ccol_base + ni * 16 + l15;
                #pragma unroll
                for (int r = 0; r < 4; ++r) {
                    const int row = crow_base + mi * 16 + lgrp * 4 + r;
                    p[(size_t)row * D + col] = acc[mi][ni][r];
                }
            }
    }
}

// ---------------- split-K reduce + Euler update (r10/r12-identical) ----------
__global__ __launch_bounds__(256) void reduce_update(
    const float* __restrict__ part, const float* __restrict__ b2,
    const float* __restrict__ z_in, float* __restrict__ z_out,
    u16* __restrict__ zh,
    float* __restrict__ traj, const float* __restrict__ tptr, int iv) {
    const int i = (blockIdx.x * 256 + threadIdx.x) * 4;
    const size_t SZ = (size_t)BS * D;
    const float4 p0 = *(const float4*)(part + i);
    const float4 p1 = *(const float4*)(part + SZ + i);
    const float4 p2 = *(const float4*)(part + 2 * SZ + i);
    const float4 p3 = *(const float4*)(part + 3 * SZ + i);
    const float4 b  = *(const float4*)(b2 + (i & (D - 1)));
    const float4 z  = *(const float4*)(z_in + i);
    const float h = fabsf(tptr[iv + 1] - tptr[iv]) * (1.0f / N_INNER);
    float4 v;
    v.x = z.x + h * (p0.x + p1.x + p2.x + p3.x + b.x);
    v.y = z.y + h * (p0.y + p1.y + p2.y + p3.y + b.y);
    v.z = z.z + h * (p0.z + p1.z + p2.z + p3.z + b.z);
    v.w = z.w + h * (p0.w + p1.w + p2.w + p3.w + b.w);
    *(float4*)(z_out + i) = v;
    u16x4 h4;
    h4.x = f2h_bits(v.x);
    h4.y = f2h_bits(v.y);
    h4.z = f2h_bits(v.z);
    h4.w = f2h_bits(v.w);
    *(u16x4*)(zh + i) = h4;
    if (traj) *(float4*)(traj + i) = v;
}

// ---------------- host ----------------

extern "C" void kernel_launch(void* const* d_in, const int* in_sizes, int n_in,
                              void* d_out, int out_size, void* d_ws, size_t ws_size,
                              hipStream_t stream) {
    const float* z0 = (const float*)d_in[0];
    const float* t  = (const float*)d_in[1];
    const float* W1 = (const float*)d_in[2];
    const float* b1 = (const float*)d_in[3];
    const float* W2 = (const float*)d_in[4];
    const float* b2 = (const float*)d_in[5];
    float* out = (float*)d_out;

    char* ws = (char*)d_ws;
    u16*   W1T_hi = (u16*)(ws);                        // [H][D] fp16, 8 MB
    u16*   W1T_lo = (u16*)(ws + (8u << 20));
    u16*   W2T_hi = (u16*)(ws + (16u << 20));          // [D][H] fp16, 8 MB
    u16*   W2T_lo = (u16*)(ws + (24u << 20));
    float* z_cur  = (float*)(ws + (32u << 20));        // [BS][D] f32
    u16*   z_h    = (u16*)(ws + (34u << 20));          // [BS][D] fp16
    u16*   hid_h  = (u16*)(ws + (36u << 20));          // [BS][H] fp16
    float* part   = (float*)(ws + (44u << 20));        // SK x [BS][D] f32, 8 MB

    transpose_split<<<dim3(H / 32, D / 32), 256, 0, stream>>>(W1, W1T_hi, W1T_lo, D, H);
    transpose_split<<<dim3(D / 32, H / 32), 256, 0, stream>>>(W2, W2T_hi, W2T_lo, H, D);
    init_z<<<(BS * D) / 256, 256, 0, stream>>>(z0, z_cur, z_h, out);

    for (int iv = 0; iv < T_STEPS - 1; ++iv) {
        for (int s = 0; s < N_INNER; ++s) {
            gemm_step<0><<<512, 256, 0, stream>>>(
                z_h, W1T_hi, W1T_lo, b1, hid_h, nullptr);
            gemm_step<1><<<512, 256, 0, stream>>>(
                hid_h, W2T_hi, W2T_lo, nullptr, nullptr, part);
            float* traj = (s == N_INNER - 1) ? out + (size_t)(iv + 1) * BS * D : nullptr;
            reduce_update<<<512, 256, 0, stream>>>(
                part, b2, z_cur, z_cur, z_h, traj, t, iv);
        }
    }
}

// Round 14
// 12222.899 us; speedup vs baseline: 1.9215x; 1.9215x over previous
//
#include <hip/hip_runtime.h>
#include <hip/hip_bf16.h>
#include <stdint.h>

#define BS 512
#define D 1024
#define H 4096
#define T_STEPS 64
#define N_INNER 4
#define SK 4

typedef __attribute__((ext_vector_type(8))) _Float16 f16x8;
typedef __attribute__((ext_vector_type(4))) float f32x4;
typedef __attribute__((ext_vector_type(4))) unsigned short u16x4;
typedef unsigned short u16;

__device__ __forceinline__ u16 f2h_bits(float f) {
    _Float16 h = (_Float16)f;
    return __builtin_bit_cast(u16, h);
}
__device__ __forceinline__ float h2f(u16 b) {
    return (float)__builtin_bit_cast(_Float16, b);
}
__device__ __forceinline__ float fast_tanh(float x) {
    float e = __expf(2.0f * x);
    return 1.0f - 2.0f / (e + 1.0f);
}

// ---------------- prep kernels ----------------

// src [rows][cols] f32 -> dst_hi/dst_lo [cols][rows] fp16 (hi + residual lo)
__global__ __launch_bounds__(256) void transpose_split(
    const float* __restrict__ src, u16* __restrict__ dst_hi,
    u16* __restrict__ dst_lo, int rows, int cols) {
    __shared__ float tile[32][33];
    const int tx = threadIdx.x & 31;
    const int ty = threadIdx.x >> 5;
    const int c0 = blockIdx.x * 32, r0 = blockIdx.y * 32;
    #pragma unroll
    for (int i = ty; i < 32; i += 8)
        tile[i][tx] = src[(size_t)(r0 + i) * cols + c0 + tx];
    __syncthreads();
    #pragma unroll
    for (int i = ty; i < 32; i += 8) {
        const float v = tile[tx][i];
        const u16 hi = f2h_bits(v);
        const u16 lo = f2h_bits(v - h2f(hi));
        const size_t idx = (size_t)(c0 + i) * rows + r0 + tx;
        dst_hi[idx] = hi;
        dst_lo[idx] = lo;
    }
}

__global__ __launch_bounds__(256) void init_z(
    const float* __restrict__ z0, float* __restrict__ z_cur,
    u16* __restrict__ z_h, float* __restrict__ out) {
    const int i = blockIdx.x * 256 + threadIdx.x;
    const float v = z0[i];
    z_cur[i] = v;
    z_h[i] = f2h_bits(v);
    out[i] = v;
}

// ---------------- B staging (rule #21 swizzle, r4/r10-proven) ----------------
// 64x64 fp16 tile (128 B rows): linear LDS dest, inverse-swizzled global src.
// 2 global_load_lds per thread.
__device__ __forceinline__ void stage_one(
    const u16* __restrict__ src, u16* lds, int row0, int ldK, int k0, int tid) {
    #pragma unroll
    for (int i = 0; i < 2; ++i) {
        const int L = (i * 256 + tid) * 16;        // byte offset in tile
        const int r = L >> 7;
        const int cb = (L & 127) ^ ((r & 7) << 4);
        const size_t goff = (size_t)(row0 + r) * ldK + k0 + (cb >> 1);
        const int ldsoff = (i * 256 + (tid & ~63)) * 8;  // elems, wave-uniform
        __builtin_amdgcn_global_load_lds(
            (const __attribute__((address_space(1))) void*)(src + goff),
            (__attribute__((address_space(3))) void*)(lds + ldsoff), 16, 0, 0);
    }
}

// ---------------- fused fp16 GEMM: A reg-prefetch depth-2, B LDS depth-3 ----
// C = A[M][K] @ BT[N][K]^T ; A single fp16 (registers, depth-2 prefetched
// global gathers — r12-proven-exact addresses, r10-proven pipeline), B split
// hi/lo staged via global_load_lds (counted vmcnt, 3 buffers).
// 64x64 tile, BK=64, 16 K-iters (fully unrolled: SSA prefetch rotation,
// static LDS buffer indices), 4 waves (2x2) of 32x32.
// Per iter: vmcnt(8) [A(kt)+B(kt) landed; A/B(kt+1) in flight] -> s_barrier
// -> issue A(kt+2) reg-gathers + B-stage(kt+2) -> ds_read B + MFMA.
// LDS traffic/blk/kt = 48 KB (r10: 72 KB).
// EPI==0: GEMM1 (K=1024, N=4096): hid = tanh(C+b1) fp16.
// EPI==1: GEMM2 split-K (4 x K=1024, N=1024): fp32 partials.
template<int EPI>
__global__ __launch_bounds__(256, 2) void gemm_step(
    const u16* __restrict__ A_h,
    const u16* __restrict__ B_hi, const u16* __restrict__ B_lo,
    const float* __restrict__ bias,
    u16* __restrict__ hid_out,
    float* __restrict__ part) {
    __shared__ __align__(16) u16 lBh[3][4096];
    __shared__ __align__(16) u16 lBl[3][4096];

    const int tid = threadIdx.x;
    const int bid = blockIdx.x;
    const int xcd = bid & 7, loc = bid >> 3;
    int tm, tn, sk, ldK;
    if (EPI == 0) {       // 8 tm x 64 tn; XCD owns 8 consecutive tn
        tn = xcd * 8 + (loc & 7);
        tm = loc >> 3;
        sk = 0;  ldK = D;
    } else {              // 4 sk x 8 tm x 16 tn; XCD owns 2 consecutive tn
        tn = xcd * 2 + (loc & 1);
        tm = (loc >> 1) & 7;
        sk = loc >> 4;  ldK = H;
    }
    const int m0 = tm * 64, n0 = tn * 64;
    const int k0b = sk * 1024;

    const int wave = tid >> 6;
    const int lane = tid & 63;
    const int wr = wave >> 1, wc = wave & 1;
    const int l15 = lane & 15;
    const int lgrp = lane >> 4;
    const int lk8 = lgrp * 8;

    // A row base pointers (r12-proven-exact fragment gather addresses)
    const u16* arow0 = A_h + (size_t)(m0 + wr * 32 + l15) * ldK + k0b + lk8;
    const u16* arow1 = arow0 + (size_t)16 * ldK;

    f32x4 acc[2][2];
    #pragma unroll
    for (int mi = 0; mi < 2; ++mi)
        #pragma unroll
        for (int ni = 0; ni < 2; ++ni)
            acc[mi][ni] = (f32x4){0.f, 0.f, 0.f, 0.f};

    auto STAGE = [&](int buf, int kt) {
        const int k0 = k0b + kt * 64;
        stage_one(B_hi, lBh[buf], n0, ldK, k0, tid);
        stage_one(B_lo, lBl[buf], n0, ldK, k0, tid);   // 4 loads/wave
    };
    auto LOADA = [&](f16x8* a, int kt) {
        const int ka = kt * 64;
        a[0] = *(const f16x8*)(arow0 + ka);        // kk=0,  mi=0
        a[1] = *(const f16x8*)(arow1 + ka);        // kk=0,  mi=1
        a[2] = *(const f16x8*)(arow0 + ka + 32);   // kk=32, mi=0
        a[3] = *(const f16x8*)(arow1 + ka + 32);   // kk=32, mi=1  (4 loads)
    };

    // prologue: A(0), B(0), A(1), B(1) — 16 VMEM ops outstanding
    f16x8 aC[4], aN[4];
    LOADA(aC, 0);
    STAGE(0, 0);
    LOADA(aN, 1);
    STAGE(1, 1);

    #pragma unroll
    for (int kt = 0; kt < 16; ++kt) {
        // steady state: 8 newest (A(kt+1)+B(kt+1)) may remain in flight
        if (kt < 15) asm volatile("s_waitcnt vmcnt(8)" ::: "memory");
        else         asm volatile("s_waitcnt vmcnt(0)" ::: "memory");
        asm volatile("s_barrier" ::: "memory");

        f16x8 aF[4];
        if (kt < 14) {
            LOADA(aF, kt + 2);            // issue A(kt+2) first (older in queue)
            STAGE((kt + 2) % 3, kt + 2);  // then B(kt+2)
        }

        const char* Bh = (const char*)lBh[kt % 3];
        const char* Bl = (const char*)lBl[kt % 3];
        #pragma unroll
        for (int kki = 0; kki < 2; ++kki) {
            const int kk = kki * 32;
            f16x8 bfh[2], bfl[2];
            #pragma unroll
            for (int ni = 0; ni < 2; ++ni) {
                const int row = wc * 32 + ni * 16 + l15;
                const int cb = ((kk + lk8) * 2) ^ ((row & 7) << 4);
                bfh[ni] = *(const f16x8*)(Bh + row * 128 + cb);
                bfl[ni] = *(const f16x8*)(Bl + row * 128 + cb);
            }
            const f16x8 af0 = aC[kki * 2];
            const f16x8 af1 = aC[kki * 2 + 1];
            #pragma unroll
            for (int ni = 0; ni < 2; ++ni) {
                acc[0][ni] = __builtin_amdgcn_mfma_f32_16x16x32_f16(
                    af0, bfh[ni], acc[0][ni], 0, 0, 0);
                acc[0][ni] = __builtin_amdgcn_mfma_f32_16x16x32_f16(
                    af0, bfl[ni], acc[0][ni], 0, 0, 0);
                acc[1][ni] = __builtin_amdgcn_mfma_f32_16x16x32_f16(
                    af1, bfh[ni], acc[1][ni], 0, 0, 0);
                acc[1][ni] = __builtin_amdgcn_mfma_f32_16x16x32_f16(
                    af1, bfl[ni], acc[1][ni], 0, 0, 0);
            }
        }
        // rotate prefetch registers (SSA under full unroll -> no moves)
        #pragma unroll
        for (int i = 0; i < 4; ++i) { aC[i] = aN[i]; aN[i] = aF[i]; }
    }

    // ---- epilogue (r10-identical) ----
    const int crow_base = m0 + wr * 32;
    const int ccol_base = n0 + wc * 32;
    if (EPI == 0) {
        #pragma unroll
        for (int mi = 0; mi < 2; ++mi)
            #pragma unroll
            for (int ni = 0; ni < 2; ++ni) {
                const int col = ccol_base + ni * 16 + l15;
                const float b = bias[col];
                #pragma unroll
                for (int r = 0; r < 4; ++r) {
                    const int row = crow_base + mi * 16 + lgrp * 4 + r;
                    const float v = fast_tanh(acc[mi][ni][r] + b);
                    hid_out[(size_t)row * H + col] = f2h_bits(v);
                }
            }
    } else {
        float* p = part + (size_t)sk * BS * D;
        #pragma unroll
        for (int mi = 0; mi < 2; ++mi)
            #pragma unroll
            for (int ni = 0; ni < 2; ++ni) {
                const int col = ccol_base + ni * 16 + l15;
                #pragma unroll
                for (int r = 0; r < 4; ++r) {
                    const int row = crow_base + mi * 16 + lgrp * 4 + r;
                    p[(size_t)row * D + col] = acc[mi][ni][r];
                }
            }
    }
}

// ---------------- split-K reduce + Euler update (r10-identical) --------------
__global__ __launch_bounds__(256) void reduce_update(
    const float* __restrict__ part, const float* __restrict__ b2,
    const float* __restrict__ z_in, float* __restrict__ z_out,
    u16* __restrict__ zh,
    float* __restrict__ traj, const float* __restrict__ tptr, int iv) {
    const int i = (blockIdx.x * 256 + threadIdx.x) * 4;
    const size_t SZ = (size_t)BS * D;
    const float4 p0 = *(const float4*)(part + i);
    const float4 p1 = *(const float4*)(part + SZ + i);
    const float4 p2 = *(const float4*)(part + 2 * SZ + i);
    const float4 p3 = *(const float4*)(part + 3 * SZ + i);
    const float4 b  = *(const float4*)(b2 + (i & (D - 1)));
    const float4 z  = *(const float4*)(z_in + i);
    const float h = fabsf(tptr[iv + 1] - tptr[iv]) * (1.0f / N_INNER);
    float4 v;
    v.x = z.x + h * (p0.x + p1.x + p2.x + p3.x + b.x);
    v.y = z.y + h * (p0.y + p1.y + p2.y + p3.y + b.y);
    v.z = z.z + h * (p0.z + p1.z + p2.z + p3.z + b.z);
    v.w = z.w + h * (p0.w + p1.w + p2.w + p3.w + b.w);
    *(float4*)(z_out + i) = v;
    u16x4 h4;
    h4.x = f2h_bits(v.x);
    h4.y = f2h_bits(v.y);
    h4.z = f2h_bits(v.z);
    h4.w = f2h_bits(v.w);
    *(u16x4*)(zh + i) = h4;
    if (traj) *(float4*)(traj + i) = v;
}

// ---------------- host ----------------

extern "C" void kernel_launch(void* const* d_in, const int* in_sizes, int n_in,
                              void* d_out, int out_size, void* d_ws, size_t ws_size,
                              hipStream_t stream) {
    const float* z0 = (const float*)d_in[0];
    const float* t  = (const float*)d_in[1];
    const float* W1 = (const float*)d_in[2];
    const float* b1 = (const float*)d_in[3];
    const float* W2 = (const float*)d_in[4];
    const float* b2 = (const float*)d_in[5];
    float* out = (float*)d_out;

    char* ws = (char*)d_ws;
    u16*   W1T_hi = (u16*)(ws);                        // [H][D] fp16, 8 MB
    u16*   W1T_lo = (u16*)(ws + (8u << 20));
    u16*   W2T_hi = (u16*)(ws + (16u << 20));          // [D][H] fp16, 8 MB
    u16*   W2T_lo = (u16*)(ws + (24u << 20));
    float* z_cur  = (float*)(ws + (32u << 20));        // [BS][D] f32
    u16*   z_h    = (u16*)(ws + (34u << 20));          // [BS][D] fp16
    u16*   hid_h  = (u16*)(ws + (36u << 20));          // [BS][H] fp16
    float* part   = (float*)(ws + (44u << 20));        // SK x [BS][D] f32, 8 MB

    transpose_split<<<dim3(H / 32, D / 32), 256, 0, stream>>>(W1, W1T_hi, W1T_lo, D, H);
    transpose_split<<<dim3(D / 32, H / 32), 256, 0, stream>>>(W2, W2T_hi, W2T_lo, H, D);
    init_z<<<(BS * D) / 256, 256, 0, stream>>>(z0, z_cur, z_h, out);

    for (int iv = 0; iv < T_STEPS - 1; ++iv) {
        for (int s = 0; s < N_INNER; ++s) {
            gemm_step<0><<<512, 256, 0, stream>>>(
                z_h, W1T_hi, W1T_lo, b1, hid_h, nullptr);
            gemm_step<1><<<512, 256, 0, stream>>>(
                hid_h, W2T_hi, W2T_lo, nullptr, nullptr, part);
            float* traj = (s == N_INNER - 1) ? out + (size_t)(iv + 1) * BS * D : nullptr;
            reduce_update<<<512, 256, 0, stream>>>(
                part, b2, z_cur, z_cur, z_h, traj, t, iv);
        }
    }
}

// Round 15
// 10111.621 us; speedup vs baseline: 2.3227x; 1.2088x over previous
//
#include <hip/hip_runtime.h>
#include <hip/hip_bf16.h>
#include <stdint.h>

#define BS 512
#define D 1024
#define H 4096
#define T_STEPS 64
#define N_INNER 4
#define SK 4

typedef __attribute__((ext_vector_type(8))) _Float16 f16x8;
typedef __attribute__((ext_vector_type(4))) float f32x4;
typedef __attribute__((ext_vector_type(4))) unsigned short u16x4;
typedef unsigned short u16;

__device__ __forceinline__ u16 f2h_bits(float f) {
    _Float16 h = (_Float16)f;
    return __builtin_bit_cast(u16, h);
}
__device__ __forceinline__ float h2f(u16 b) {
    return (float)__builtin_bit_cast(_Float16, b);
}
__device__ __forceinline__ float fast_tanh(float x) {
    float e = __expf(2.0f * x);
    return 1.0f - 2.0f / (e + 1.0f);
}
// system-scope f32 store: bypasses XCD L1/L2 -> coherent LLC (r7-proven path)
__device__ __forceinline__ void st_f32_sys(float* p, float v) {
    asm volatile("global_store_dword %0, %1, off sc0 sc1"
                 :: "v"(p), "v"(v) : "memory");
}
// LLC-coherent read (r7-proven: relaxed agent-scope loads observe remote
// sc1 writes; no cache-maintenance side effects)
__device__ __forceinline__ float ld_f32_sys(const float* p) {
    return __hip_atomic_load(p, __ATOMIC_RELAXED, __HIP_MEMORY_SCOPE_AGENT);
}

// ---------------- prep kernels ----------------

// src [rows][cols] f32 -> dst_hi/dst_lo [cols][rows] fp16 (hi + residual lo)
__global__ __launch_bounds__(256) void transpose_split(
    const float* __restrict__ src, u16* __restrict__ dst_hi,
    u16* __restrict__ dst_lo, int rows, int cols) {
    __shared__ float tile[32][33];
    const int tx = threadIdx.x & 31;
    const int ty = threadIdx.x >> 5;
    const int c0 = blockIdx.x * 32, r0 = blockIdx.y * 32;
    #pragma unroll
    for (int i = ty; i < 32; i += 8)
        tile[i][tx] = src[(size_t)(r0 + i) * cols + c0 + tx];
    __syncthreads();
    #pragma unroll
    for (int i = ty; i < 32; i += 8) {
        const float v = tile[tx][i];
        const u16 hi = f2h_bits(v);
        const u16 lo = f2h_bits(v - h2f(hi));
        const size_t idx = (size_t)(c0 + i) * rows + r0 + tx;
        dst_hi[idx] = hi;
        dst_lo[idx] = lo;
    }
}

// also zeroes the 128 split-K tile counters
__global__ __launch_bounds__(256) void init_z(
    const float* __restrict__ z0, float* __restrict__ z_cur,
    u16* __restrict__ z_h, float* __restrict__ out, unsigned* __restrict__ cnt) {
    const int i = blockIdx.x * 256 + threadIdx.x;
    const float v = z0[i];
    z_cur[i] = v;
    z_h[i] = f2h_bits(v);
    out[i] = v;
    if (i < 128) cnt[i] = 0u;
}

// ---------------- staging helper (rule #21 swizzle, r4/r10-proven) -----------
// 64x64 fp16 tile (128 B rows): linear LDS dest, inverse-swizzled global src.
__device__ __forceinline__ void stage_one(
    const u16* __restrict__ src, u16* lds, int row0, int ldK, int k0, int tid) {
    #pragma unroll
    for (int i = 0; i < 2; ++i) {
        const int L = (i * 256 + tid) * 16;        // byte offset in tile
        const int r = L >> 7;
        const int cb = (L & 127) ^ ((r & 7) << 4);
        const size_t goff = (size_t)(row0 + r) * ldK + k0 + (cb >> 1);
        const int ldsoff = (i * 256 + (tid & ~63)) * 8;  // elems, wave-uniform
        __builtin_amdgcn_global_load_lds(
            (const __attribute__((address_space(1))) void*)(src + goff),
            (__attribute__((address_space(3))) void*)(lds + ldsoff), 16, 0, 0);
    }
}

// ---------------- fused fp16 GEMM (r10 K-loop verbatim) ----------------------
// C = A[M][K] @ BT[N][K]^T ; A single fp16, B split hi/lo (2 MFMA terms).
// 64x64 tile, BK=64, 16 K-iters, 4 waves (2x2) of 32x32; depth-3 LDS
// pipeline with counted vmcnt(6) (never drains mid-loop).
// EPI==0: GEMM1 (K=1024, N=4096): hid = tanh(C+b1) fp16.
// EPI==1: GEMM2 split-K (4 x K=1024, N=1024): sc1 partials + relaxed agent
//         counter; last-arriving block of each tile reduces (LLC-coherent
//         reads) + fused Euler/traj epilogue.
template<int EPI>
__global__ __launch_bounds__(256, 2) void gemm_step(
    const u16* __restrict__ A_h,
    const u16* __restrict__ B_hi, const u16* __restrict__ B_lo,
    const float* __restrict__ bias,
    u16* __restrict__ hid_out,
    float* __restrict__ part, unsigned* __restrict__ cnt,
    float* __restrict__ z_cur, u16* __restrict__ zh_out,
    float* __restrict__ traj,
    const float* __restrict__ tptr, int iv, int step) {
    __shared__ __align__(16) u16 lA[3][4096];
    __shared__ __align__(16) u16 lBh[3][4096];
    __shared__ __align__(16) u16 lBl[3][4096];
    __shared__ unsigned sflag;

    const int tid = threadIdx.x;
    const int bid = blockIdx.x;
    const int xcd = bid & 7, loc = bid >> 3;
    int tm, tn, sk, ldK;
    if (EPI == 0) {       // 8 tm x 64 tn; XCD owns 8 consecutive tn
        tn = xcd * 8 + (loc & 7);
        tm = loc >> 3;
        sk = 0;  ldK = D;
    } else {              // 4 sk x 8 tm x 16 tn; XCD owns 2 consecutive tn
        tn = xcd * 2 + (loc & 1);
        tm = (loc >> 1) & 7;
        sk = loc >> 4;  ldK = H;
    }
    const int m0 = tm * 64, n0 = tn * 64;
    const int k0b = sk * 1024;

    const int wave = tid >> 6;
    const int lane = tid & 63;
    const int wr = wave >> 1, wc = wave & 1;
    const int l15 = lane & 15;
    const int lgrp = lane >> 4;
    const int lk8 = lgrp * 8;

    f32x4 acc[2][2];
    #pragma unroll
    for (int mi = 0; mi < 2; ++mi)
        #pragma unroll
        for (int ni = 0; ni < 2; ++ni)
            acc[mi][ni] = (f32x4){0.f, 0.f, 0.f, 0.f};

    auto STAGE = [&](int buf, int kt) {
        const int k0 = k0b + kt * 64;
        stage_one(A_h,  lA[buf],  m0, ldK, k0, tid);
        stage_one(B_hi, lBh[buf], n0, ldK, k0, tid);
        stage_one(B_lo, lBl[buf], n0, ldK, k0, tid);   // 6 loads/wave total
    };
    auto COMPUTE = [&](int buf) {
        const char* Ah = (const char*)lA[buf];
        const char* Bh = (const char*)lBh[buf];
        const char* Bl = (const char*)lBl[buf];
        #pragma unroll
        for (int kk = 0; kk < 64; kk += 32) {
            f16x8 af[2], bfh[2], bfl[2];
            #pragma unroll
            for (int mi = 0; mi < 2; ++mi) {
                const int row = wr * 32 + mi * 16 + l15;
                const int cb = ((kk + lk8) * 2) ^ ((row & 7) << 4);
                af[mi] = *(const f16x8*)(Ah + row * 128 + cb);
            }
            #pragma unroll
            for (int ni = 0; ni < 2; ++ni) {
                const int row = wc * 32 + ni * 16 + l15;
                const int cb = ((kk + lk8) * 2) ^ ((row & 7) << 4);
                bfh[ni] = *(const f16x8*)(Bh + row * 128 + cb);
                bfl[ni] = *(const f16x8*)(Bl + row * 128 + cb);
            }
            #pragma unroll
            for (int mi = 0; mi < 2; ++mi)
                #pragma unroll
                for (int ni = 0; ni < 2; ++ni) {
                    acc[mi][ni] = __builtin_amdgcn_mfma_f32_16x16x32_f16(
                        af[mi], bfh[ni], acc[mi][ni], 0, 0, 0);
                    acc[mi][ni] = __builtin_amdgcn_mfma_f32_16x16x32_f16(
                        af[mi], bfl[ni], acc[mi][ni], 0, 0, 0);
                }
        }
    };

    // r10-verbatim depth-3 pipeline
    STAGE(0, 0);
    STAGE(1, 1);
    int cur = 0;
    for (int kt = 0; kt < 14; ++kt) {
        asm volatile("s_waitcnt vmcnt(6)" ::: "memory");  // stage kt landed
        asm volatile("s_barrier" ::: "memory");
        int nb = cur + 2; if (nb >= 3) nb -= 3;
        STAGE(nb, kt + 2);
        COMPUTE(cur);
        ++cur; if (cur == 3) cur = 0;
    }
    asm volatile("s_waitcnt vmcnt(6)" ::: "memory");
    asm volatile("s_barrier" ::: "memory");
    COMPUTE(cur);
    ++cur; if (cur == 3) cur = 0;
    asm volatile("s_waitcnt vmcnt(0)" ::: "memory");
    asm volatile("s_barrier" ::: "memory");
    COMPUTE(cur);

    // ---- epilogue ----
    const int crow_base = m0 + wr * 32;
    const int ccol_base = n0 + wc * 32;
    if (EPI == 0) {
        #pragma unroll
        for (int mi = 0; mi < 2; ++mi)
            #pragma unroll
            for (int ni = 0; ni < 2; ++ni) {
                const int col = ccol_base + ni * 16 + l15;
                const float b = bias[col];
                #pragma unroll
                for (int r = 0; r < 4; ++r) {
                    const int row = crow_base + mi * 16 + lgrp * 4 + r;
                    const float v = fast_tanh(acc[mi][ni][r] + b);
                    hid_out[(size_t)row * H + col] = f2h_bits(v);
                }
            }
    } else {
        // 1) publish this block's fp32 partial tile to LLC (sc0sc1)
        float* p = part + (size_t)sk * BS * D;
        #pragma unroll
        for (int mi = 0; mi < 2; ++mi)
            #pragma unroll
            for (int ni = 0; ni < 2; ++ni) {
                const int col = ccol_base + ni * 16 + l15;
                #pragma unroll
                for (int r = 0; r < 4; ++r) {
                    const int row = crow_base + mi * 16 + lgrp * 4 + r;
                    st_f32_sys(p + (size_t)row * D + col, acc[mi][ni][r]);
                }
            }
        // 2) drain stores to LLC, then arrive (relaxed: no cache maintenance)
        asm volatile("s_waitcnt vmcnt(0)" ::: "memory");
        __syncthreads();
        const int tile = tm * 16 + tn;
        if (tid == 0) {
            sflag = __hip_atomic_fetch_add(&cnt[tile], 1u,
                        __ATOMIC_RELAXED, __HIP_MEMORY_SCOPE_AGENT);
        }
        __syncthreads();
        // 3) last arriver reduces via LLC-coherent loads + Euler update
        if (sflag == (unsigned)(step * 4 + 3)) {
            const float hstep = fabsf(tptr[iv + 1] - tptr[iv]) * (1.0f / N_INNER);
            const size_t SZ = (size_t)BS * D;
            const int r = tid >> 2;                    // 0..63
            const int c0 = (tid & 3) * 16;             // 0/16/32/48
            const size_t base = (size_t)(m0 + r) * D + n0 + c0;
            #pragma unroll
            for (int c4 = 0; c4 < 4; ++c4) {
                const size_t off = base + c4 * 4;
                const float* q0 = part + off;
                const float* q1 = part + SZ + off;
                const float* q2 = part + 2 * SZ + off;
                const float* q3 = part + 3 * SZ + off;
                const float4 bb = *(const float4*)(bias + n0 + c0 + c4 * 4);
                const float4 zz = *(const float4*)(z_cur + off);
                float4 v;
                v.x = zz.x + hstep * (ld_f32_sys(q0 + 0) + ld_f32_sys(q1 + 0)
                                    + ld_f32_sys(q2 + 0) + ld_f32_sys(q3 + 0) + bb.x);
                v.y = zz.y + hstep * (ld_f32_sys(q0 + 1) + ld_f32_sys(q1 + 1)
                                    + ld_f32_sys(q2 + 1) + ld_f32_sys(q3 + 1) + bb.y);
                v.z = zz.z + hstep * (ld_f32_sys(q0 + 2) + ld_f32_sys(q1 + 2)
                                    + ld_f32_sys(q2 + 2) + ld_f32_sys(q3 + 2) + bb.z);
                v.w = zz.w + hstep * (ld_f32_sys(q0 + 3) + ld_f32_sys(q1 + 3)
                                    + ld_f32_sys(q2 + 3) + ld_f32_sys(q3 + 3) + bb.w);
                *(float4*)(z_cur + off) = v;
                u16x4 h4;
                h4.x = f2h_bits(v.x);
                h4.y = f2h_bits(v.y);
                h4.z = f2h_bits(v.z);
                h4.w = f2h_bits(v.w);
                *(u16x4*)(zh_out + off) = h4;
                if (traj) *(float4*)(traj + off) = v;
            }
        }
    }
}

// ---------------- host ----------------

extern "C" void kernel_launch(void* const* d_in, const int* in_sizes, int n_in,
                              void* d_out, int out_size, void* d_ws, size_t ws_size,
                              hipStream_t stream) {
    const float* z0 = (const float*)d_in[0];
    const float* t  = (const float*)d_in[1];
    const float* W1 = (const float*)d_in[2];
    const float* b1 = (const float*)d_in[3];
    const float* W2 = (const float*)d_in[4];
    const float* b2 = (const float*)d_in[5];
    float* out = (float*)d_out;

    char* ws = (char*)d_ws;
    u16*      W1T_hi = (u16*)(ws);                      // [H][D] fp16, 8 MB
    u16*      W1T_lo = (u16*)(ws + (8u << 20));
    u16*      W2T_hi = (u16*)(ws + (16u << 20));        // [D][H] fp16, 8 MB
    u16*      W2T_lo = (u16*)(ws + (24u << 20));
    float*    z_cur  = (float*)(ws + (32u << 20));      // [BS][D] f32
    u16*      z_h    = (u16*)(ws + (34u << 20));        // [BS][D] fp16
    u16*      hid_h  = (u16*)(ws + (36u << 20));        // [BS][H] fp16
    float*    part   = (float*)(ws + (44u << 20));      // SK x [BS][D] f32, 8 MB
    unsigned* cnt    = (unsigned*)(ws + (52u << 20));   // 128 tile counters

    transpose_split<<<dim3(H / 32, D / 32), 256, 0, stream>>>(W1, W1T_hi, W1T_lo, D, H);
    transpose_split<<<dim3(D / 32, H / 32), 256, 0, stream>>>(W2, W2T_hi, W2T_lo, H, D);
    init_z<<<(BS * D) / 256, 256, 0, stream>>>(z0, z_cur, z_h, out, cnt);

    for (int iv = 0; iv < T_STEPS - 1; ++iv) {
        for (int s = 0; s < N_INNER; ++s) {
            const int step = iv * N_INNER + s;
            gemm_step<0><<<512, 256, 0, stream>>>(
                z_h, W1T_hi, W1T_lo, b1, hid_h,
                nullptr, nullptr, nullptr, nullptr, nullptr, nullptr, 0, 0);
            float* traj = (s == N_INNER - 1) ? out + (size_t)(iv + 1) * BS * D
                                             : nullptr;
            gemm_step<1><<<512, 256, 0, stream>>>(
                hid_h, W2T_hi, W2T_lo, b2, nullptr,
                part, cnt, z_cur, z_h, traj, t, iv, step);
        }
    }
}

// Round 16
// 7858.421 us; speedup vs baseline: 2.9887x; 1.2867x over previous
//
#include <hip/hip_runtime.h>
#include <hip/hip_bf16.h>
#include <stdint.h>

#define BS 512
#define D 1024
#define H 4096
#define T_STEPS 64
#define N_INNER 4
#define SK 4

typedef __attribute__((ext_vector_type(8))) _Float16 f16x8;
typedef __attribute__((ext_vector_type(4))) float f32x4;
typedef __attribute__((ext_vector_type(4))) unsigned short u16x4;
typedef unsigned short u16;

__device__ __forceinline__ u16 f2h_bits(float f) {
    _Float16 h = (_Float16)f;
    return __builtin_bit_cast(u16, h);
}
__device__ __forceinline__ float h2f(u16 b) {
    return (float)__builtin_bit_cast(_Float16, b);
}
__device__ __forceinline__ float fast_tanh(float x) {
    float e = __expf(2.0f * x);
    return 1.0f - 2.0f / (e + 1.0f);
}

// ---------------- prep kernels ----------------

// src [rows][cols] f32 -> dst [cols][rows] single fp16 (for W1)
__global__ __launch_bounds__(256) void transpose_h(
    const float* __restrict__ src, u16* __restrict__ dst, int rows, int cols) {
    __shared__ float tile[32][33];
    const int tx = threadIdx.x & 31;
    const int ty = threadIdx.x >> 5;
    const int c0 = blockIdx.x * 32, r0 = blockIdx.y * 32;
    #pragma unroll
    for (int i = ty; i < 32; i += 8)
        tile[i][tx] = src[(size_t)(r0 + i) * cols + c0 + tx];
    __syncthreads();
    #pragma unroll
    for (int i = ty; i < 32; i += 8)
        dst[(size_t)(c0 + i) * rows + r0 + tx] = f2h_bits(tile[tx][i]);
}

// src [rows][cols] f32 -> dst_hi/dst_lo [cols][rows] fp16 hi+lo (for W2)
__global__ __launch_bounds__(256) void transpose_split(
    const float* __restrict__ src, u16* __restrict__ dst_hi,
    u16* __restrict__ dst_lo, int rows, int cols) {
    __shared__ float tile[32][33];
    const int tx = threadIdx.x & 31;
    const int ty = threadIdx.x >> 5;
    const int c0 = blockIdx.x * 32, r0 = blockIdx.y * 32;
    #pragma unroll
    for (int i = ty; i < 32; i += 8)
        tile[i][tx] = src[(size_t)(r0 + i) * cols + c0 + tx];
    __syncthreads();
    #pragma unroll
    for (int i = ty; i < 32; i += 8) {
        const float v = tile[tx][i];
        const u16 hi = f2h_bits(v);
        const u16 lo = f2h_bits(v - h2f(hi));
        const size_t idx = (size_t)(c0 + i) * rows + r0 + tx;
        dst_hi[idx] = hi;
        dst_lo[idx] = lo;
    }
}

__global__ __launch_bounds__(256) void init_z(
    const float* __restrict__ z0, float* __restrict__ z_cur,
    u16* __restrict__ z_h, float* __restrict__ out) {
    const int i = blockIdx.x * 256 + threadIdx.x;
    const float v = z0[i];
    z_cur[i] = v;
    z_h[i] = f2h_bits(v);
    out[i] = v;
}

// ---------------- staging helper (rule #21 swizzle, r4/r10-proven) -----------
// 64x64 fp16 tile (128 B rows): linear LDS dest, inverse-swizzled global src.
__device__ __forceinline__ void stage_one(
    const u16* __restrict__ src, u16* lds, int row0, int ldK, int k0, int tid) {
    #pragma unroll
    for (int i = 0; i < 2; ++i) {
        const int L = (i * 256 + tid) * 16;        // byte offset in tile
        const int r = L >> 7;
        const int cb = (L & 127) ^ ((r & 7) << 4);
        const size_t goff = (size_t)(row0 + r) * ldK + k0 + (cb >> 1);
        const int ldsoff = (i * 256 + (tid & ~63)) * 8;  // elems, wave-uniform
        __builtin_amdgcn_global_load_lds(
            (const __attribute__((address_space(1))) void*)(src + goff),
            (__attribute__((address_space(3))) void*)(lds + ldsoff), 16, 0, 0);
    }
}

// ---------------- GEMM1: hid = tanh(z @ W1 + b1), single-fp16 W1 ------------
// 64x64 tile, BK=64, 16 K-iters, 4 waves (2x2) of 32x32; depth-3 LDS
// pipeline, counted vmcnt(4) (2 streams x 2 loads per stage).
__global__ __launch_bounds__(256, 2) void gemm1_step(
    const u16* __restrict__ A_h, const u16* __restrict__ B_w,
    const float* __restrict__ bias, u16* __restrict__ hid_out) {
    __shared__ __align__(16) u16 lA[3][4096];
    __shared__ __align__(16) u16 lB[3][4096];

    const int tid = threadIdx.x;
    const int bid = blockIdx.x;
    const int xcd = bid & 7, loc = bid >> 3;
    const int tn = xcd * 8 + (loc & 7);   // XCD owns 8 consecutive tn
    const int tm = loc >> 3;
    const int m0 = tm * 64, n0 = tn * 64;

    const int wave = tid >> 6;
    const int lane = tid & 63;
    const int wr = wave >> 1, wc = wave & 1;
    const int l15 = lane & 15;
    const int lgrp = lane >> 4;
    const int lk8 = lgrp * 8;

    f32x4 acc[2][2];
    #pragma unroll
    for (int mi = 0; mi < 2; ++mi)
        #pragma unroll
        for (int ni = 0; ni < 2; ++ni)
            acc[mi][ni] = (f32x4){0.f, 0.f, 0.f, 0.f};

    auto STAGE = [&](int buf, int kt) {
        const int k0 = kt * 64;
        stage_one(A_h, lA[buf], m0, D, k0, tid);
        stage_one(B_w, lB[buf], n0, D, k0, tid);      // 4 loads/wave total
    };
    auto COMPUTE = [&](int buf) {
        const char* Ah = (const char*)lA[buf];
        const char* Bh = (const char*)lB[buf];
        #pragma unroll
        for (int kk = 0; kk < 64; kk += 32) {
            f16x8 af[2], bf[2];
            #pragma unroll
            for (int mi = 0; mi < 2; ++mi) {
                const int row = wr * 32 + mi * 16 + l15;
                const int cb = ((kk + lk8) * 2) ^ ((row & 7) << 4);
                af[mi] = *(const f16x8*)(Ah + row * 128 + cb);
            }
            #pragma unroll
            for (int ni = 0; ni < 2; ++ni) {
                const int row = wc * 32 + ni * 16 + l15;
                const int cb = ((kk + lk8) * 2) ^ ((row & 7) << 4);
                bf[ni] = *(const f16x8*)(Bh + row * 128 + cb);
            }
            #pragma unroll
            for (int mi = 0; mi < 2; ++mi)
                #pragma unroll
                for (int ni = 0; ni < 2; ++ni)
                    acc[mi][ni] = __builtin_amdgcn_mfma_f32_16x16x32_f16(
                        af[mi], bf[ni], acc[mi][ni], 0, 0, 0);
        }
    };

    STAGE(0, 0);
    STAGE(1, 1);
    int cur = 0;
    for (int kt = 0; kt < 14; ++kt) {
        asm volatile("s_waitcnt vmcnt(4)" ::: "memory");  // stage kt landed
        asm volatile("s_barrier" ::: "memory");
        int nb = cur + 2; if (nb >= 3) nb -= 3;
        STAGE(nb, kt + 2);
        COMPUTE(cur);
        ++cur; if (cur == 3) cur = 0;
    }
    asm volatile("s_waitcnt vmcnt(4)" ::: "memory");
    asm volatile("s_barrier" ::: "memory");
    COMPUTE(cur);
    ++cur; if (cur == 3) cur = 0;
    asm volatile("s_waitcnt vmcnt(0)" ::: "memory");
    asm volatile("s_barrier" ::: "memory");
    COMPUTE(cur);

    const int crow_base = m0 + wr * 32;
    const int ccol_base = n0 + wc * 32;
    #pragma unroll
    for (int mi = 0; mi < 2; ++mi)
        #pragma unroll
        for (int ni = 0; ni < 2; ++ni) {
            const int col = ccol_base + ni * 16 + l15;
            const float b = bias[col];
            #pragma unroll
            for (int r = 0; r < 4; ++r) {
                const int row = crow_base + mi * 16 + lgrp * 4 + r;
                const float v = fast_tanh(acc[mi][ni][r] + b);
                hid_out[(size_t)row * H + col] = f2h_bits(v);
            }
        }
}

// ---------------- GEMM2: split-K partials, W2 split hi/lo (r10-verbatim) -----
__global__ __launch_bounds__(256, 2) void gemm2_step(
    const u16* __restrict__ A_h,
    const u16* __restrict__ B_hi, const u16* __restrict__ B_lo,
    float* __restrict__ part) {
    __shared__ __align__(16) u16 lA[3][4096];
    __shared__ __align__(16) u16 lBh[3][4096];
    __shared__ __align__(16) u16 lBl[3][4096];

    const int tid = threadIdx.x;
    const int bid = blockIdx.x;
    const int xcd = bid & 7, loc = bid >> 3;
    const int tn = xcd * 2 + (loc & 1);   // XCD owns 2 consecutive tn
    const int tm = (loc >> 1) & 7;
    const int sk = loc >> 4;
    const int m0 = tm * 64, n0 = tn * 64;
    const int k0b = sk * 1024;

    const int wave = tid >> 6;
    const int lane = tid & 63;
    const int wr = wave >> 1, wc = wave & 1;
    const int l15 = lane & 15;
    const int lgrp = lane >> 4;
    const int lk8 = lgrp * 8;

    f32x4 acc[2][2];
    #pragma unroll
    for (int mi = 0; mi < 2; ++mi)
        #pragma unroll
        for (int ni = 0; ni < 2; ++ni)
            acc[mi][ni] = (f32x4){0.f, 0.f, 0.f, 0.f};

    auto STAGE = [&](int buf, int kt) {
        const int k0 = k0b + kt * 64;
        stage_one(A_h,  lA[buf],  m0, H, k0, tid);
        stage_one(B_hi, lBh[buf], n0, H, k0, tid);
        stage_one(B_lo, lBl[buf], n0, H, k0, tid);    // 6 loads/wave total
    };
    auto COMPUTE = [&](int buf) {
        const char* Ah = (const char*)lA[buf];
        const char* Bh = (const char*)lBh[buf];
        const char* Bl = (const char*)lBl[buf];
        #pragma unroll
        for (int kk = 0; kk < 64; kk += 32) {
            f16x8 af[2], bfh[2], bfl[2];
            #pragma unroll
            for (int mi = 0; mi < 2; ++mi) {
                const int row = wr * 32 + mi * 16 + l15;
                const int cb = ((kk + lk8) * 2) ^ ((row & 7) << 4);
                af[mi] = *(const f16x8*)(Ah + row * 128 + cb);
            }
            #pragma unroll
            for (int ni = 0; ni < 2; ++ni) {
                const int row = wc * 32 + ni * 16 + l15;
                const int cb = ((kk + lk8) * 2) ^ ((row & 7) << 4);
                bfh[ni] = *(const f16x8*)(Bh + row * 128 + cb);
                bfl[ni] = *(const f16x8*)(Bl + row * 128 + cb);
            }
            #pragma unroll
            for (int mi = 0; mi < 2; ++mi)
                #pragma unroll
                for (int ni = 0; ni < 2; ++ni) {
                    acc[mi][ni] = __builtin_amdgcn_mfma_f32_16x16x32_f16(
                        af[mi], bfh[ni], acc[mi][ni], 0, 0, 0);
                    acc[mi][ni] = __builtin_amdgcn_mfma_f32_16x16x32_f16(
                        af[mi], bfl[ni], acc[mi][ni], 0, 0, 0);
                }
        }
    };

    STAGE(0, 0);
    STAGE(1, 1);
    int cur = 0;
    for (int kt = 0; kt < 14; ++kt) {
        asm volatile("s_waitcnt vmcnt(6)" ::: "memory");
        asm volatile("s_barrier" ::: "memory");
        int nb = cur + 2; if (nb >= 3) nb -= 3;
        STAGE(nb, kt + 2);
        COMPUTE(cur);
        ++cur; if (cur == 3) cur = 0;
    }
    asm volatile("s_waitcnt vmcnt(6)" ::: "memory");
    asm volatile("s_barrier" ::: "memory");
    COMPUTE(cur);
    ++cur; if (cur == 3) cur = 0;
    asm volatile("s_waitcnt vmcnt(0)" ::: "memory");
    asm volatile("s_barrier" ::: "memory");
    COMPUTE(cur);

    float* p = part + (size_t)sk * BS * D;
    const int crow_base = m0 + wr * 32;
    const int ccol_base = n0 + wc * 32;
    #pragma unroll
    for (int mi = 0; mi < 2; ++mi)
        #pragma unroll
        for (int ni = 0; ni < 2; ++ni) {
            const int col = ccol_base + ni * 16 + l15;
            #pragma unroll
            for (int r = 0; r < 4; ++r) {
                const int row = crow_base + mi * 16 + lgrp * 4 + r;
                p[(size_t)row * D + col] = acc[mi][ni][r];
            }
        }
}

// ---------------- split-K reduce + Euler update (r10-identical) --------------
__global__ __launch_bounds__(256) void reduce_update(
    const float* __restrict__ part, const float* __restrict__ b2,
    const float* __restrict__ z_in, float* __restrict__ z_out,
    u16* __restrict__ zh,
    float* __restrict__ traj, const float* __restrict__ tptr, int iv) {
    const int i = (blockIdx.x * 256 + threadIdx.x) * 4;
    const size_t SZ = (size_t)BS * D;
    const float4 p0 = *(const float4*)(part + i);
    const float4 p1 = *(const float4*)(part + SZ + i);
    const float4 p2 = *(const float4*)(part + 2 * SZ + i);
    const float4 p3 = *(const float4*)(part + 3 * SZ + i);
    const float4 b  = *(const float4*)(b2 + (i & (D - 1)));
    const float4 z  = *(const float4*)(z_in + i);
    const float h = fabsf(tptr[iv + 1] - tptr[iv]) * (1.0f / N_INNER);
    float4 v;
    v.x = z.x + h * (p0.x + p1.x + p2.x + p3.x + b.x);
    v.y = z.y + h * (p0.y + p1.y + p2.y + p3.y + b.y);
    v.z = z.z + h * (p0.z + p1.z + p2.z + p3.z + b.z);
    v.w = z.w + h * (p0.w + p1.w + p2.w + p3.w + b.w);
    *(float4*)(z_out + i) = v;
    u16x4 h4;
    h4.x = f2h_bits(v.x);
    h4.y = f2h_bits(v.y);
    h4.z = f2h_bits(v.z);
    h4.w = f2h_bits(v.w);
    *(u16x4*)(zh + i) = h4;
    if (traj) *(float4*)(traj + i) = v;
}

// ---------------- host ----------------

extern "C" void kernel_launch(void* const* d_in, const int* in_sizes, int n_in,
                              void* d_out, int out_size, void* d_ws, size_t ws_size,
                              hipStream_t stream) {
    const float* z0 = (const float*)d_in[0];
    const float* t  = (const float*)d_in[1];
    const float* W1 = (const float*)d_in[2];
    const float* b1 = (const float*)d_in[3];
    const float* W2 = (const float*)d_in[4];
    const float* b2 = (const float*)d_in[5];
    float* out = (float*)d_out;

    char* ws = (char*)d_ws;
    u16*   W1T    = (u16*)(ws);                        // [H][D] fp16, 8 MB
    u16*   W2T_hi = (u16*)(ws + (16u << 20));          // [D][H] fp16, 8 MB
    u16*   W2T_lo = (u16*)(ws + (24u << 20));
    float* z_cur  = (float*)(ws + (32u << 20));        // [BS][D] f32
    u16*   z_h    = (u16*)(ws + (34u << 20));          // [BS][D] fp16
    u16*   hid_h  = (u16*)(ws + (36u << 20));          // [BS][H] fp16
    float* part   = (float*)(ws + (44u << 20));        // SK x [BS][D] f32, 8 MB

    transpose_h<<<dim3(H / 32, D / 32), 256, 0, stream>>>(W1, W1T, D, H);
    transpose_split<<<dim3(D / 32, H / 32), 256, 0, stream>>>(W2, W2T_hi, W2T_lo, H, D);
    init_z<<<(BS * D) / 256, 256, 0, stream>>>(z0, z_cur, z_h, out);

    for (int iv = 0; iv < T_STEPS - 1; ++iv) {
        for (int s = 0; s < N_INNER; ++s) {
            gemm1_step<<<512, 256, 0, stream>>>(z_h, W1T, b1, hid_h);
            gemm2_step<<<512, 256, 0, stream>>>(hid_h, W2T_hi, W2T_lo, part);
            float* traj = (s == N_INNER - 1) ? out + (size_t)(iv + 1) * BS * D : nullptr;
            reduce_update<<<512, 256, 0, stream>>>(
                part, b2, z_cur, z_cur, z_h, traj, t, iv);
        }
    }
}

// Round 17
// 7527.208 us; speedup vs baseline: 3.1202x; 1.0440x over previous
//
#include <hip/hip_runtime.h>
#include <hip/hip_bf16.h>
#include <stdint.h>

#define BS 512
#define D 1024
#define H 4096
#define T_STEPS 64
#define N_INNER 4
#define SK 8

typedef __attribute__((ext_vector_type(8))) _Float16 f16x8;
typedef __attribute__((ext_vector_type(4))) float f32x4;
typedef __attribute__((ext_vector_type(4))) unsigned short u16x4;
typedef unsigned short u16;

__device__ __forceinline__ u16 f2h_bits(float f) {
    _Float16 h = (_Float16)f;
    return __builtin_bit_cast(u16, h);
}
__device__ __forceinline__ float h2f(u16 b) {
    return (float)__builtin_bit_cast(_Float16, b);
}
__device__ __forceinline__ float fast_tanh(float x) {
    float e = __expf(2.0f * x);
    return 1.0f - 2.0f / (e + 1.0f);
}

// ---------------- prep kernels ----------------

// src [rows][cols] f32 -> dst [cols][rows] single fp16 (for W1)
__global__ __launch_bounds__(256) void transpose_h(
    const float* __restrict__ src, u16* __restrict__ dst, int rows, int cols) {
    __shared__ float tile[32][33];
    const int tx = threadIdx.x & 31;
    const int ty = threadIdx.x >> 5;
    const int c0 = blockIdx.x * 32, r0 = blockIdx.y * 32;
    #pragma unroll
    for (int i = ty; i < 32; i += 8)
        tile[i][tx] = src[(size_t)(r0 + i) * cols + c0 + tx];
    __syncthreads();
    #pragma unroll
    for (int i = ty; i < 32; i += 8)
        dst[(size_t)(c0 + i) * rows + r0 + tx] = f2h_bits(tile[tx][i]);
}

// src [rows][cols] f32 -> dst_hi/dst_lo [cols][rows] fp16 hi+lo (for W2)
__global__ __launch_bounds__(256) void transpose_split(
    const float* __restrict__ src, u16* __restrict__ dst_hi,
    u16* __restrict__ dst_lo, int rows, int cols) {
    __shared__ float tile[32][33];
    const int tx = threadIdx.x & 31;
    const int ty = threadIdx.x >> 5;
    const int c0 = blockIdx.x * 32, r0 = blockIdx.y * 32;
    #pragma unroll
    for (int i = ty; i < 32; i += 8)
        tile[i][tx] = src[(size_t)(r0 + i) * cols + c0 + tx];
    __syncthreads();
    #pragma unroll
    for (int i = ty; i < 32; i += 8) {
        const float v = tile[tx][i];
        const u16 hi = f2h_bits(v);
        const u16 lo = f2h_bits(v - h2f(hi));
        const size_t idx = (size_t)(c0 + i) * rows + r0 + tx;
        dst_hi[idx] = hi;
        dst_lo[idx] = lo;
    }
}

__global__ __launch_bounds__(256) void init_z(
    const float* __restrict__ z0, float* __restrict__ z_cur,
    u16* __restrict__ z_h, float* __restrict__ out) {
    const int i = blockIdx.x * 256 + threadIdx.x;
    const float v = z0[i];
    z_cur[i] = v;
    z_h[i] = f2h_bits(v);
    out[i] = v;
}

// ---------------- staging helpers (rule #21 swizzle, r4/r10-proven) ----------
// NR rows x 64 cols fp16 (128 B rows): linear LDS dest, inverse-swizzled src.
template<int NISS>
__device__ __forceinline__ void stage_rows(
    const u16* __restrict__ src, u16* lds, int row0, int ldK, int k0, int tid) {
    #pragma unroll
    for (int i = 0; i < NISS; ++i) {
        const int L = (i * 256 + tid) * 16;        // byte offset in tile
        const int r = L >> 7;
        const int cb = (L & 127) ^ ((r & 7) << 4);
        const size_t goff = (size_t)(row0 + r) * ldK + k0 + (cb >> 1);
        const int ldsoff = (i * 256 + (tid & ~63)) * 8;  // elems, wave-uniform
        __builtin_amdgcn_global_load_lds(
            (const __attribute__((address_space(1))) void*)(src + goff),
            (__attribute__((address_space(3))) void*)(lds + ldsoff), 16, 0, 0);
    }
}

// ---------------- GEMM1 (r16-verbatim): hid = tanh(z @ W1 + b1) --------------
// 64x64 tile, BK=64, 16 K-iters, 4 waves (2x2) of 32x32; depth-3 LDS
// pipeline, counted vmcnt(4).
__global__ __launch_bounds__(256, 2) void gemm1_step(
    const u16* __restrict__ A_h, const u16* __restrict__ B_w,
    const float* __restrict__ bias, u16* __restrict__ hid_out) {
    __shared__ __align__(16) u16 lA[3][4096];
    __shared__ __align__(16) u16 lB[3][4096];

    const int tid = threadIdx.x;
    const int bid = blockIdx.x;
    const int xcd = bid & 7, loc = bid >> 3;
    const int tn = xcd * 8 + (loc & 7);
    const int tm = loc >> 3;
    const int m0 = tm * 64, n0 = tn * 64;

    const int wave = tid >> 6;
    const int lane = tid & 63;
    const int wr = wave >> 1, wc = wave & 1;
    const int l15 = lane & 15;
    const int lgrp = lane >> 4;
    const int lk8 = lgrp * 8;

    f32x4 acc[2][2];
    #pragma unroll
    for (int mi = 0; mi < 2; ++mi)
        #pragma unroll
        for (int ni = 0; ni < 2; ++ni)
            acc[mi][ni] = (f32x4){0.f, 0.f, 0.f, 0.f};

    auto STAGE = [&](int buf, int kt) {
        const int k0 = kt * 64;
        stage_rows<2>(A_h, lA[buf], m0, D, k0, tid);
        stage_rows<2>(B_w, lB[buf], n0, D, k0, tid);  // 4 loads/wave total
    };
    auto COMPUTE = [&](int buf) {
        const char* Ah = (const char*)lA[buf];
        const char* Bh = (const char*)lB[buf];
        #pragma unroll
        for (int kk = 0; kk < 64; kk += 32) {
            f16x8 af[2], bf[2];
            #pragma unroll
            for (int mi = 0; mi < 2; ++mi) {
                const int row = wr * 32 + mi * 16 + l15;
                const int cb = ((kk + lk8) * 2) ^ ((row & 7) << 4);
                af[mi] = *(const f16x8*)(Ah + row * 128 + cb);
            }
            #pragma unroll
            for (int ni = 0; ni < 2; ++ni) {
                const int row = wc * 32 + ni * 16 + l15;
                const int cb = ((kk + lk8) * 2) ^ ((row & 7) << 4);
                bf[ni] = *(const f16x8*)(Bh + row * 128 + cb);
            }
            #pragma unroll
            for (int mi = 0; mi < 2; ++mi)
                #pragma unroll
                for (int ni = 0; ni < 2; ++ni)
                    acc[mi][ni] = __builtin_amdgcn_mfma_f32_16x16x32_f16(
                        af[mi], bf[ni], acc[mi][ni], 0, 0, 0);
        }
    };

    STAGE(0, 0);
    STAGE(1, 1);
    int cur = 0;
    for (int kt = 0; kt < 14; ++kt) {
        asm volatile("s_waitcnt vmcnt(4)" ::: "memory");
        asm volatile("s_barrier" ::: "memory");
        int nb = cur + 2; if (nb >= 3) nb -= 3;
        STAGE(nb, kt + 2);
        COMPUTE(cur);
        ++cur; if (cur == 3) cur = 0;
    }
    asm volatile("s_waitcnt vmcnt(4)" ::: "memory");
    asm volatile("s_barrier" ::: "memory");
    COMPUTE(cur);
    ++cur; if (cur == 3) cur = 0;
    asm volatile("s_waitcnt vmcnt(0)" ::: "memory");
    asm volatile("s_barrier" ::: "memory");
    COMPUTE(cur);

    const int crow_base = m0 + wr * 32;
    const int ccol_base = n0 + wc * 32;
    #pragma unroll
    for (int mi = 0; mi < 2; ++mi)
        #pragma unroll
        for (int ni = 0; ni < 2; ++ni) {
            const int col = ccol_base + ni * 16 + l15;
            const float b = bias[col];
            #pragma unroll
            for (int r = 0; r < 4; ++r) {
                const int row = crow_base + mi * 16 + lgrp * 4 + r;
                const float v = fast_tanh(acc[mi][ni][r] + b);
                hid_out[(size_t)row * H + col] = f2h_bits(v);
            }
        }
}

// ---------------- GEMM2: 128x64 tile, SK=8, W2 split hi/lo -------------------
// BM=128, BN=64, BK=64, K-slice=512 (8 kt). 4 waves (2x2), each 64x32
// (acc 4x2). Depth-2 double-buffer (64 KB LDS -> 2 blocks/CU), counted
// vmcnt(8) (8 loads/wave/stage: A 4 + Bhi 2 + Blo 2), 2 barriers/iter.
// Per-output LDS traffic 2/3 of the 64x64 variant.
__global__ __launch_bounds__(256, 2) void gemm2_step(
    const u16* __restrict__ A_h,
    const u16* __restrict__ B_hi, const u16* __restrict__ B_lo,
    float* __restrict__ part) {
    __shared__ __align__(16) u16 lA[2][8192];     // 128x64
    __shared__ __align__(16) u16 lBh[2][4096];    // 64x64
    __shared__ __align__(16) u16 lBl[2][4096];

    const int tid = threadIdx.x;
    const int bid = blockIdx.x;
    const int xcd = bid & 7, loc = bid >> 3;      // loc 0..63
    const int tn = xcd * 2 + (loc & 1);           // 0..15
    const int tm = (loc >> 1) & 3;                // 0..3
    const int sk = loc >> 3;                      // 0..7
    const int m0 = tm * 128, n0 = tn * 64;
    const int k0b = sk * 512;

    const int wave = tid >> 6;
    const int lane = tid & 63;
    const int wr = wave >> 1, wc = wave & 1;      // wave owns 64x32
    const int l15 = lane & 15;
    const int lgrp = lane >> 4;
    const int lk8 = lgrp * 8;

    f32x4 acc[4][2];
    #pragma unroll
    for (int mi = 0; mi < 4; ++mi)
        #pragma unroll
        for (int ni = 0; ni < 2; ++ni)
            acc[mi][ni] = (f32x4){0.f, 0.f, 0.f, 0.f};

    auto STAGE = [&](int buf, int kt) {
        const int k0 = k0b + kt * 64;
        stage_rows<4>(A_h,  lA[buf],  m0, H, k0, tid);
        stage_rows<2>(B_hi, lBh[buf], n0, H, k0, tid);
        stage_rows<2>(B_lo, lBl[buf], n0, H, k0, tid);   // 8 loads/wave
    };
    auto COMPUTE = [&](int buf) {
        const char* Ah = (const char*)lA[buf];
        const char* Bh = (const char*)lBh[buf];
        const char* Bl = (const char*)lBl[buf];
        #pragma unroll
        for (int kk = 0; kk < 64; kk += 32) {
            f16x8 af[4], bfh[2], bfl[2];
            #pragma unroll
            for (int mi = 0; mi < 4; ++mi) {
                const int row = wr * 64 + mi * 16 + l15;
                const int cb = ((kk + lk8) * 2) ^ ((row & 7) << 4);
                af[mi] = *(const f16x8*)(Ah + row * 128 + cb);
            }
            #pragma unroll
            for (int ni = 0; ni < 2; ++ni) {
                const int row = wc * 32 + ni * 16 + l15;
                const int cb = ((kk + lk8) * 2) ^ ((row & 7) << 4);
                bfh[ni] = *(const f16x8*)(Bh + row * 128 + cb);
                bfl[ni] = *(const f16x8*)(Bl + row * 128 + cb);
            }
            #pragma unroll
            for (int mi = 0; mi < 4; ++mi)
                #pragma unroll
                for (int ni = 0; ni < 2; ++ni) {
                    acc[mi][ni] = __builtin_amdgcn_mfma_f32_16x16x32_f16(
                        af[mi], bfh[ni], acc[mi][ni], 0, 0, 0);
                    acc[mi][ni] = __builtin_amdgcn_mfma_f32_16x16x32_f16(
                        af[mi], bfl[ni], acc[mi][ni], 0, 0, 0);
                }
        }
    };

    // depth-2 pipeline over 8 kt: stage kt+1 in flight during compute kt;
    // buffer cur is re-staged (kt+2) only after the post-compute barrier.
    STAGE(0, 0);
    STAGE(1, 1);
    int cur = 0;
    for (int kt = 0; kt < 8; ++kt) {
        if (kt < 7) asm volatile("s_waitcnt vmcnt(8)" ::: "memory");
        else        asm volatile("s_waitcnt vmcnt(0)" ::: "memory");
        asm volatile("s_barrier" ::: "memory");
        COMPUTE(cur);
        if (kt < 6) {
            asm volatile("s_barrier" ::: "memory");   // all waves done with cur
            STAGE(cur, kt + 2);
        }
        cur ^= 1;
    }

    float* p = part + (size_t)sk * BS * D;
    const int crow_base = m0 + wr * 64;
    const int ccol_base = n0 + wc * 32;
    #pragma unroll
    for (int mi = 0; mi < 4; ++mi)
        #pragma unroll
        for (int ni = 0; ni < 2; ++ni) {
            const int col = ccol_base + ni * 16 + l15;
            #pragma unroll
            for (int r = 0; r < 4; ++r) {
                const int row = crow_base + mi * 16 + lgrp * 4 + r;
                p[(size_t)row * D + col] = acc[mi][ni][r];
            }
        }
}

// ---------------- split-K reduce (SK=8) + Euler update -----------------------
__global__ __launch_bounds__(256) void reduce_update(
    const float* __restrict__ part, const float* __restrict__ b2,
    const float* __restrict__ z_in, float* __restrict__ z_out,
    u16* __restrict__ zh,
    float* __restrict__ traj, const float* __restrict__ tptr, int iv) {
    const int i = (blockIdx.x * 256 + threadIdx.x) * 4;
    const size_t SZ = (size_t)BS * D;
    float4 s = *(const float4*)(part + i);
    #pragma unroll
    for (int k = 1; k < SK; ++k) {
        const float4 pk = *(const float4*)(part + (size_t)k * SZ + i);
        s.x += pk.x; s.y += pk.y; s.z += pk.z; s.w += pk.w;
    }
    const float4 b = *(const float4*)(b2 + (i & (D - 1)));
    const float4 z = *(const float4*)(z_in + i);
    const float h = fabsf(tptr[iv + 1] - tptr[iv]) * (1.0f / N_INNER);
    float4 v;
    v.x = z.x + h * (s.x + b.x);
    v.y = z.y + h * (s.y + b.y);
    v.z = z.z + h * (s.z + b.z);
    v.w = z.w + h * (s.w + b.w);
    *(float4*)(z_out + i) = v;
    u16x4 h4;
    h4.x = f2h_bits(v.x);
    h4.y = f2h_bits(v.y);
    h4.z = f2h_bits(v.z);
    h4.w = f2h_bits(v.w);
    *(u16x4*)(zh + i) = h4;
    if (traj) *(float4*)(traj + i) = v;
}

// ---------------- host ----------------

extern "C" void kernel_launch(void* const* d_in, const int* in_sizes, int n_in,
                              void* d_out, int out_size, void* d_ws, size_t ws_size,
                              hipStream_t stream) {
    const float* z0 = (const float*)d_in[0];
    const float* t  = (const float*)d_in[1];
    const float* W1 = (const float*)d_in[2];
    const float* b1 = (const float*)d_in[3];
    const float* W2 = (const float*)d_in[4];
    const float* b2 = (const float*)d_in[5];
    float* out = (float*)d_out;

    char* ws = (char*)d_ws;
    u16*   W1T    = (u16*)(ws);                        // [H][D] fp16, 8 MB
    u16*   W2T_hi = (u16*)(ws + (8u << 20));           // [D][H] fp16, 8 MB
    u16*   W2T_lo = (u16*)(ws + (16u << 20));
    float* z_cur  = (float*)(ws + (24u << 20));        // [BS][D] f32, 2 MB
    u16*   z_h    = (u16*)(ws + (26u << 20));          // [BS][D] fp16, 1 MB
    u16*   hid_h  = (u16*)(ws + (28u << 20));          // [BS][H] fp16, 4 MB
    float* part   = (float*)(ws + (32u << 20));        // SK x [BS][D] f32, 16 MB

    transpose_h<<<dim3(H / 32, D / 32), 256, 0, stream>>>(W1, W1T, D, H);
    transpose_split<<<dim3(D / 32, H / 32), 256, 0, stream>>>(W2, W2T_hi, W2T_lo, H, D);
    init_z<<<(BS * D) / 256, 256, 0, stream>>>(z0, z_cur, z_h, out);

    for (int iv = 0; iv < T_STEPS - 1; ++iv) {
        for (int s = 0; s < N_INNER; ++s) {
            gemm1_step<<<512, 256, 0, stream>>>(z_h, W1T, b1, hid_h);
            gemm2_step<<<512, 256, 0, stream>>>(hid_h, W2T_hi, W2T_lo, part);
            float* traj = (s == N_INNER - 1) ? out + (size_t)(iv + 1) * BS * D : nullptr;
            reduce_update<<<512, 256, 0, stream>>>(
                part, b2, z_cur, z_cur, z_h, traj, t, iv);
        }
    }
}